// Round 8
// baseline (137.937 us; speedup 1.0000x reference)
//
#include <hip/hip_runtime.h>
#include <hip/hip_bf16.h>
#include <math.h>

#define SEQ   1024
#define DH    64
#define KBLK  64
#define NBH   128
#define LDK   72   // LDS row stride (shorts)
#define C2    0.1803368801111244f   // 0.125 * log2(e)
#define DEFER_THR 44.0f

typedef short bf16x8 __attribute__((ext_vector_type(8)));
typedef float f32x4  __attribute__((ext_vector_type(4)));
typedef unsigned u32x4 __attribute__((ext_vector_type(4)));

__device__ inline unsigned short f2bf_rne(float f) {
    union { float f; unsigned u; } x; x.f = f;
    unsigned u = x.u;
    u += 0x7FFFu + ((u >> 16) & 1u);
    return (unsigned short)(u >> 16);
}
__device__ inline unsigned cvt_pk_bf16(float lo, float hi) {
    unsigned r;
    asm("v_cvt_pk_bf16_f32 %0, %1, %2" : "=v"(r) : "v"(lo), "v"(hi));
    return r;
}
// NOTE: operands must be DISTINCT values — never call with a==b (register
// coalescing would fuse them into one VGPR and the swap self-permutes).
__device__ inline void pl32swap(unsigned &a, unsigned &b) {
    asm("v_permlane32_swap_b32 %0, %1" : "+v"(a), "+v"(b));
}
__device__ inline void pl16swap(unsigned &a, unsigned &b) {
    asm("v_permlane16_swap_b32 %0, %1" : "+v"(a), "+v"(b));
}

// reductions over the 4 16-lane groups: allocation-independent shfl_xor path
__device__ inline float wave_red_add(float x) {
    x += __shfl_xor(x, 16);
    x += __shfl_xor(x, 32);
    return x;
}
__device__ inline float wave_red_max(float x) {
    x = fmaxf(x, __shfl_xor(x, 16));
    x = fmaxf(x, __shfl_xor(x, 32));
    return x;
}

// ---- pre-pass: K -> bf16 flat [bh][kk][d]; V -> bf16 transposed tiled [bh][kt][d][kk] ----
__global__ __launch_bounds__(256)
void conv_kv(const float* __restrict__ K, const float* __restrict__ V,
             unsigned short* __restrict__ Kb, unsigned short* __restrict__ Vt) {
    __shared__ unsigned short T[DH][LDK];
    const int kt  = blockIdx.x;
    const int bh  = blockIdx.y;
    const int tid = threadIdx.x;
    const size_t tile = ((size_t)bh * SEQ + kt * KBLK) * DH;

    const float* Ks = K + tile;
    unsigned short* Kd = Kb + tile;
    #pragma unroll
    for (int it = 0; it < 4; ++it) {
        const int e = (it * 256 + tid) * 4;
        float4 f = *(const float4*)(Ks + e);
        union { unsigned short s[4]; uint2 u; } p;
        p.s[0] = f2bf_rne(f.x); p.s[1] = f2bf_rne(f.y);
        p.s[2] = f2bf_rne(f.z); p.s[3] = f2bf_rne(f.w);
        *(uint2*)(Kd + e) = p.u;
    }
    const float* Vs = V + tile;
    #pragma unroll
    for (int it = 0; it < 4; ++it) {
        const int e = (it * 256 + tid) * 4;
        const int kk = e >> 6, d = e & 63;
        float4 f = *(const float4*)(Vs + e);
        T[d + 0][kk] = f2bf_rne(f.x);
        T[d + 1][kk] = f2bf_rne(f.y);
        T[d + 2][kk] = f2bf_rne(f.z);
        T[d + 3][kk] = f2bf_rne(f.w);
    }
    __syncthreads();
    unsigned short* Vd = Vt + tile;
    #pragma unroll
    for (int it = 0; it < 2; ++it) {
        const int e = (it * 256 + tid) * 8;
        const int d = e >> 6, kk0 = e & 63;
        uint4 o = *(const uint4*)&T[d][kk0];
        *(uint4*)(Vd + d * KBLK + kk0) = o;
    }
}

// ---- main kernel: 128-row q blocks, 32 q/wave; K via dbuf LDS, V via register
//      prefetch (one-tile slack hides L2 latency); l via MFMA-of-ones ----
__global__ __launch_bounds__(256, 4)
void attn_fwd(const float* __restrict__ Q,
              const unsigned short* __restrict__ Kb,
              const unsigned short* __restrict__ Vt,
              float* __restrict__ O) {
    __shared__ unsigned short Ksh[2][KBLK][LDK];

    // XCD-chunked swizzle: all 8 q-tiles of one bh on one XCD (1024 % 8 == 0)
    const int f  = blockIdx.y * 8 + blockIdx.x;
    const int w  = (f & 7) * 128 + (f >> 3);
    const int qt = w & 7;          // 0..7 (128-row tiles)
    const int bh = w >> 3;

    const int tid  = threadIdx.x;
    const int wave = tid >> 6;
    const int lane = tid & 63;
    const int lhi  = lane >> 4;
    const int llo  = lane & 15;

    const float* Qb = Q + ((size_t)bh * SEQ + qt * 128) * DH;
    float*       Ob = O + ((size_t)bh * SEQ + qt * 128) * DH;

    // Two Q fragment sets: set A = rows wave*32 + llo, set B = +16
    bf16x8 qfA[2], qfB[2];
    #pragma unroll
    for (int s = 0; s < 2; ++s) {
        const float* pa = Qb + (wave * 32 + llo) * DH + s * 32 + lhi * 8;
        const float* pb = pa + 16 * DH;
        float4 a0 = *(const float4*)(pa), a1 = *(const float4*)(pa + 4);
        float4 b0 = *(const float4*)(pb), b1 = *(const float4*)(pb + 4);
        qfA[s][0]=(short)f2bf_rne(a0.x); qfA[s][1]=(short)f2bf_rne(a0.y);
        qfA[s][2]=(short)f2bf_rne(a0.z); qfA[s][3]=(short)f2bf_rne(a0.w);
        qfA[s][4]=(short)f2bf_rne(a1.x); qfA[s][5]=(short)f2bf_rne(a1.y);
        qfA[s][6]=(short)f2bf_rne(a1.z); qfA[s][7]=(short)f2bf_rne(a1.w);
        qfB[s][0]=(short)f2bf_rne(b0.x); qfB[s][1]=(short)f2bf_rne(b0.y);
        qfB[s][2]=(short)f2bf_rne(b0.z); qfB[s][3]=(short)f2bf_rne(b0.w);
        qfB[s][4]=(short)f2bf_rne(b1.x); qfB[s][5]=(short)f2bf_rne(b1.y);
        qfB[s][6]=(short)f2bf_rne(b1.z); qfB[s][7]=(short)f2bf_rne(b1.w);
    }

    // ones B-fragment for row-sum MFMA (bf16 1.0 = 0x3F80)
    const bf16x8 ones = {0x3F80, 0x3F80, 0x3F80, 0x3F80,
                         0x3F80, 0x3F80, 0x3F80, 0x3F80};

    // K staging geometry: 256 threads x 2 uint4 per tile (64x64 shorts)
    const unsigned short* KbB = Kb + (size_t)bh * SEQ * DH;
    const unsigned short* VtB = Vt + (size_t)bh * SEQ * DH;
    const int soff = tid * 8;              // shorts
    const int srow = tid >> 3;             // 0..31
    const int scol = (tid & 7) * 8;

    // per-lane V fragment base (wave-uniform across waves -> L1 broadcast)
    const unsigned short* Vl = VtB + llo * KBLK + lhi * 8;

    // prologue: stage K tile 0 into buf 0; V tile 0 into registers
    uint4 k0r = *(const uint4*)(KbB + soff);
    uint4 k1r = *(const uint4*)(KbB + 2048 + soff);
    *(uint4*)&Ksh[0][srow][scol]      = k0r;
    *(uint4*)&Ksh[0][32 + srow][scol] = k1r;
    bf16x8 vf[4][2];
    #pragma unroll
    for (int dt = 0; dt < 4; ++dt) {
        vf[dt][0] = *(const bf16x8*)(Vl + dt * 16 * KBLK);
        vf[dt][1] = *(const bf16x8*)(Vl + dt * 16 * KBLK + 32);
    }
    __syncthreads();

    f32x4 accA[4] = {}, accB[4] = {};
    f32x4 accLA = {}, accLB = {};          // row-sums (l), same C-layout as acc
    float mCA = 0.0f, mCB = 0.0f;          // fixed (tile-0) per-row max * C2

    for (int kt = 0; kt < SEQ / KBLK; ++kt) {
        const int cur = kt & 1;

        // ---- issue next K tile's global loads (consumed by ds_write below) ----
        if (kt < 15) {
            const unsigned short* Kt = KbB + (kt + 1) * (KBLK * DH);
            k0r = *(const uint4*)(Kt + soff);
            k1r = *(const uint4*)(Kt + 2048 + soff);
        }

        // ---- QK^T: each K fragment read feeds both q-sets ----
        f32x4 stA[4] = {}, stB[4] = {};
        __builtin_amdgcn_s_setprio(1);
        #pragma unroll
        for (int t = 0; t < 4; ++t) {
            bf16x8 k0 = *(const bf16x8*)&Ksh[cur][t * 16 + llo][lhi * 8];
            bf16x8 k1 = *(const bf16x8*)&Ksh[cur][t * 16 + llo][32 + lhi * 8];
            stA[t] = __builtin_amdgcn_mfma_f32_16x16x32_bf16(k0, qfA[0], stA[t], 0, 0, 0);
            stA[t] = __builtin_amdgcn_mfma_f32_16x16x32_bf16(k1, qfA[1], stA[t], 0, 0, 0);
            stB[t] = __builtin_amdgcn_mfma_f32_16x16x32_bf16(k0, qfB[0], stB[t], 0, 0, 0);
            stB[t] = __builtin_amdgcn_mfma_f32_16x16x32_bf16(k1, qfB[1], stB[t], 0, 0, 0);
        }
        __builtin_amdgcn_s_setprio(0);

        // ---- fixed-M: per-q-row max from tile 0 (softmax shift-invariant) ----
        if (kt == 0) {
            float ta = stA[0][0], tb = stB[0][0];
            #pragma unroll
            for (int t = 0; t < 4; ++t)
                #pragma unroll
                for (int r = 0; r < 4; ++r) {
                    ta = fmaxf(ta, stA[t][r]);
                    tb = fmaxf(tb, stB[t][r]);
                }
            mCA = wave_red_max(ta) * C2;
            mCB = wave_red_max(tb) * C2;
        }

        // ---- P = exp2(S*C2 - mC), packed bf16, in-register ----
        unsigned wrA[4][2], wrB[4][2];
        #pragma unroll
        for (int t = 0; t < 4; ++t) {
            float a0 = __builtin_amdgcn_exp2f(__builtin_fmaf(stA[t][0], C2, -mCA));
            float a1 = __builtin_amdgcn_exp2f(__builtin_fmaf(stA[t][1], C2, -mCA));
            float a2 = __builtin_amdgcn_exp2f(__builtin_fmaf(stA[t][2], C2, -mCA));
            float a3 = __builtin_amdgcn_exp2f(__builtin_fmaf(stA[t][3], C2, -mCA));
            wrA[t][0] = cvt_pk_bf16(a0, a1);
            wrA[t][1] = cvt_pk_bf16(a2, a3);
            float b0 = __builtin_amdgcn_exp2f(__builtin_fmaf(stB[t][0], C2, -mCB));
            float b1 = __builtin_amdgcn_exp2f(__builtin_fmaf(stB[t][1], C2, -mCB));
            float b2 = __builtin_amdgcn_exp2f(__builtin_fmaf(stB[t][2], C2, -mCB));
            float b3 = __builtin_amdgcn_exp2f(__builtin_fmaf(stB[t][3], C2, -mCB));
            wrB[t][0] = cvt_pk_bf16(b0, b1);
            wrB[t][1] = cvt_pk_bf16(b2, b3);
        }

        // ---- in-register P relayout -> A-fragments (operands always distinct) ----
        unsigned pa0 = wrA[0][0], pb0 = wrA[1][0]; pl32swap(pa0, pb0); pl16swap(pa0, pb0);
        unsigned pa1 = wrA[0][1], pb1 = wrA[1][1]; pl32swap(pa1, pb1); pl16swap(pa1, pb1);
        unsigned pc0 = wrA[2][0], pd0 = wrA[3][0]; pl32swap(pc0, pd0); pl16swap(pc0, pd0);
        unsigned pc1 = wrA[2][1], pd1 = wrA[3][1]; pl32swap(pc1, pd1); pl16swap(pc1, pd1);
        bf16x8 afA0 = __builtin_bit_cast(bf16x8, (u32x4){pa0, pa1, pb0, pb1});
        bf16x8 afA1 = __builtin_bit_cast(bf16x8, (u32x4){pc0, pc1, pd0, pd1});
        unsigned qa0 = wrB[0][0], qb0 = wrB[1][0]; pl32swap(qa0, qb0); pl16swap(qa0, qb0);
        unsigned qa1 = wrB[0][1], qb1 = wrB[1][1]; pl32swap(qa1, qb1); pl16swap(qa1, qb1);
        unsigned qc0 = wrB[2][0], qd0 = wrB[3][0]; pl32swap(qc0, qd0); pl16swap(qc0, qd0);
        unsigned qc1 = wrB[2][1], qd1 = wrB[3][1]; pl32swap(qc1, qd1); pl16swap(qc1, qd1);
        bf16x8 afB0 = __builtin_bit_cast(bf16x8, (u32x4){qa0, qa1, qb0, qb1});
        bf16x8 afB1 = __builtin_bit_cast(bf16x8, (u32x4){qc0, qc1, qd0, qd1});

        // ---- PV from registers + l via MFMA-of-ones ----
        __builtin_amdgcn_s_setprio(1);
        #pragma unroll
        for (int dt = 0; dt < 4; ++dt) {
            accA[dt] = __builtin_amdgcn_mfma_f32_16x16x32_bf16(afA0, vf[dt][0], accA[dt], 0, 0, 0);
            accA[dt] = __builtin_amdgcn_mfma_f32_16x16x32_bf16(afA1, vf[dt][1], accA[dt], 0, 0, 0);
            accB[dt] = __builtin_amdgcn_mfma_f32_16x16x32_bf16(afB0, vf[dt][0], accB[dt], 0, 0, 0);
            accB[dt] = __builtin_amdgcn_mfma_f32_16x16x32_bf16(afB1, vf[dt][1], accB[dt], 0, 0, 0);
        }
        accLA = __builtin_amdgcn_mfma_f32_16x16x32_bf16(afA0, ones, accLA, 0, 0, 0);
        accLA = __builtin_amdgcn_mfma_f32_16x16x32_bf16(afA1, ones, accLA, 0, 0, 0);
        accLB = __builtin_amdgcn_mfma_f32_16x16x32_bf16(afB0, ones, accLB, 0, 0, 0);
        accLB = __builtin_amdgcn_mfma_f32_16x16x32_bf16(afB1, ones, accLB, 0, 0, 0);
        __builtin_amdgcn_s_setprio(0);

        // ---- V prefetch for t+1 into the SAME registers (PV already read them);
        //      consumed next iter after QK+softmax -> latency hidden ----
        if (kt < 15) {
            const unsigned short* Vp = Vl + (kt + 1) * (KBLK * DH);
            #pragma unroll
            for (int dt = 0; dt < 4; ++dt) {
                vf[dt][0] = *(const bf16x8*)(Vp + dt * 16 * KBLK);
                vf[dt][1] = *(const bf16x8*)(Vp + dt * 16 * KBLK + 32);
            }
        }

        // ---- write next K tile into the other buffer; single barrier ----
        if (kt < 15) {
            const int nxt = cur ^ 1;
            *(uint4*)&Ksh[nxt][srow][scol]      = k0r;
            *(uint4*)&Ksh[nxt][32 + srow][scol] = k1r;
        }
        __syncthreads();
    }

    // ---- epilogue: accL already in acc's C-layout -> direct divide, no shfl ----
    #pragma unroll
    for (int r = 0; r < 4; ++r) {
        const float la = 1.0f / accLA[r];
        const float lb = 1.0f / accLB[r];
        const int rowA = wave * 32 + lhi * 4 + r;
        #pragma unroll
        for (int dt = 0; dt < 4; ++dt) {
            Ob[rowA * DH + dt * 16 + llo]        = accA[dt][r] * la;
            Ob[(rowA + 16) * DH + dt * 16 + llo] = accB[dt][r] * lb;
        }
    }
}

// ---- fallback (ws too small): round-5 self-staging kernel ----
__global__ __launch_bounds__(256)
void attn_fwd_fb(const float* __restrict__ Q, const float* __restrict__ K,
                 const float* __restrict__ V, float* __restrict__ O) {
    __shared__ unsigned short Ksh[KBLK][LDK];
    __shared__ unsigned short Vsh[DH][LDK];

    const int f  = blockIdx.y * 16 + blockIdx.x;
    const int w  = (f & 7) * 256 + (f >> 3);
    const int qt = w & 15;
    const int bh = w >> 4;

    const int tid  = threadIdx.x;
    const int wave = tid >> 6;
    const int lane = tid & 63;
    const int lhi  = lane >> 4;
    const int llo  = lane & 15;
    const int base = lane & 48;

    const float* Qb = Q + ((size_t)bh * SEQ + qt * 64) * DH;
    float*       Ob = O + ((size_t)bh * SEQ + qt * 64) * DH;

    bf16x8 qf[2];
    #pragma unroll
    for (int s = 0; s < 2; ++s) {
        const float* p = Qb + (wave * 16 + llo) * DH + s * 32 + lhi * 8;
        float4 f0 = *(const float4*)(p), f1 = *(const float4*)(p + 4);
        qf[s][0]=(short)f2bf_rne(f0.x); qf[s][1]=(short)f2bf_rne(f0.y);
        qf[s][2]=(short)f2bf_rne(f0.z); qf[s][3]=(short)f2bf_rne(f0.w);
        qf[s][4]=(short)f2bf_rne(f1.x); qf[s][5]=(short)f2bf_rne(f1.y);
        qf[s][6]=(short)f2bf_rne(f1.z); qf[s][7]=(short)f2bf_rne(f1.w);
    }

    f32x4 acc[4] = {};
    float m_run = -INFINITY, l_run = 0.0f;

    for (int kt = 0; kt < SEQ / KBLK; ++kt) {
        __syncthreads();
        {
            const float* Kt = K + ((size_t)bh * SEQ + kt * KBLK) * DH;
            const float* Vs = V + ((size_t)bh * SEQ + kt * KBLK) * DH;
            #pragma unroll
            for (int it = 0; it < 4; ++it) {
                const int e  = (it * 256 + tid) * 4;
                const int kk = e >> 6, d = e & 63;
                float4 kv = *(const float4*)(Kt + e);
                union { unsigned short s[4]; uint2 u; } pk;
                pk.s[0] = f2bf_rne(kv.x); pk.s[1] = f2bf_rne(kv.y);
                pk.s[2] = f2bf_rne(kv.z); pk.s[3] = f2bf_rne(kv.w);
                *(uint2*)&Ksh[kk][d] = pk.u;
                float4 vv = *(const float4*)(Vs + e);
                Vsh[d + 0][kk] = f2bf_rne(vv.x);
                Vsh[d + 1][kk] = f2bf_rne(vv.y);
                Vsh[d + 2][kk] = f2bf_rne(vv.z);
                Vsh[d + 3][kk] = f2bf_rne(vv.w);
            }
        }
        __syncthreads();

        f32x4 st[4] = {};
        #pragma unroll
        for (int t = 0; t < 4; ++t) {
            bf16x8 k0 = *(const bf16x8*)&Ksh[t * 16 + llo][lhi * 8];
            bf16x8 k1 = *(const bf16x8*)&Ksh[t * 16 + llo][32 + lhi * 8];
            st[t] = __builtin_amdgcn_mfma_f32_16x16x32_bf16(k0, qf[0], st[t], 0, 0, 0);
            st[t] = __builtin_amdgcn_mfma_f32_16x16x32_bf16(k1, qf[1], st[t], 0, 0, 0);
        }

        float tmax = st[0][0];
        #pragma unroll
        for (int t = 0; t < 4; ++t)
            #pragma unroll
            for (int r = 0; r < 4; ++r) tmax = fmaxf(tmax, st[t][r]);
        tmax = wave_red_max(tmax);

        if (__any(tmax > m_run + DEFER_THR)) {
            float mn   = fmaxf(m_run, tmax);
            float corr = exp2f((m_run - mn) * C2);
            m_run = mn;
            l_run *= corr;
            #pragma unroll
            for (int r = 0; r < 4; ++r) {
                float cr = __shfl(corr, base | (lhi * 4 + r));
                #pragma unroll
                for (int dt = 0; dt < 4; ++dt) acc[dt][r] *= cr;
            }
        }

        const float mC = m_run * C2;
        float tsum = 0.0f;
        unsigned wreg[4][2];
        #pragma unroll
        for (int t = 0; t < 4; ++t) {
            float p0 = __builtin_amdgcn_exp2f(__builtin_fmaf(st[t][0], C2, -mC));
            float p1 = __builtin_amdgcn_exp2f(__builtin_fmaf(st[t][1], C2, -mC));
            float p2 = __builtin_amdgcn_exp2f(__builtin_fmaf(st[t][2], C2, -mC));
            float p3 = __builtin_amdgcn_exp2f(__builtin_fmaf(st[t][3], C2, -mC));
            tsum += (p0 + p1) + (p2 + p3);
            wreg[t][0] = cvt_pk_bf16(p0, p1);
            wreg[t][1] = cvt_pk_bf16(p2, p3);
        }
        l_run += wave_red_add(tsum);

        unsigned a0 = wreg[0][0], b0 = wreg[1][0]; pl32swap(a0, b0); pl16swap(a0, b0);
        unsigned a1 = wreg[0][1], b1 = wreg[1][1]; pl32swap(a1, b1); pl16swap(a1, b1);
        unsigned c0 = wreg[2][0], d0 = wreg[3][0]; pl32swap(c0, d0); pl16swap(c0, d0);
        unsigned c1 = wreg[2][1], d1 = wreg[3][1]; pl32swap(c1, d1); pl16swap(c1, d1);
        bf16x8 af0 = __builtin_bit_cast(bf16x8, (u32x4){a0, a1, b0, b1});
        bf16x8 af1 = __builtin_bit_cast(bf16x8, (u32x4){c0, c1, d0, d1});

        #pragma unroll
        for (int dt = 0; dt < 4; ++dt) {
            bf16x8 v0 = *(const bf16x8*)&Vsh[dt * 16 + llo][lhi * 8];
            bf16x8 v1 = *(const bf16x8*)&Vsh[dt * 16 + llo][32 + lhi * 8];
            acc[dt] = __builtin_amdgcn_mfma_f32_16x16x32_bf16(af0, v0, acc[dt], 0, 0, 0);
            acc[dt] = __builtin_amdgcn_mfma_f32_16x16x32_bf16(af1, v1, acc[dt], 0, 0, 0);
        }
    }

    const float linv = 1.0f / l_run;
    #pragma unroll
    for (int r = 0; r < 4; ++r) {
        const float lr = __shfl(linv, base | (lhi * 4 + r));
        const int row = wave * 16 + lhi * 4 + r;
        #pragma unroll
        for (int dt = 0; dt < 4; ++dt)
            Ob[row * DH + dt * 16 + llo] = acc[dt][r] * lr;
    }
}

extern "C" void kernel_launch(void* const* d_in, const int* in_sizes, int n_in,
                              void* d_out, int out_size, void* d_ws, size_t ws_size,
                              hipStream_t stream) {
    const float* q = (const float*)d_in[0];
    const float* k = (const float*)d_in[1];
    const float* v = (const float*)d_in[2];
    float* o = (float*)d_out;

    const size_t nkv = (size_t)NBH * SEQ * DH;
    dim3 block(256);

    if (ws_size >= 2 * nkv * sizeof(unsigned short)) {
        unsigned short* Kb = (unsigned short*)d_ws;
        unsigned short* Vt = Kb + nkv;
        dim3 cgrid(SEQ / KBLK, NBH);
        conv_kv<<<cgrid, block, 0, stream>>>(k, v, Kb, Vt);
        dim3 agrid(SEQ / 128, NBH);
        attn_fwd<<<agrid, block, 0, stream>>>(q, Kb, Vt, o);
    } else {
        dim3 fgrid(SEQ / 64, NBH);
        attn_fwd_fb<<<fgrid, block, 0, stream>>>(q, k, v, o);
    }
}

// Round 9
// 90.146 us; speedup vs baseline: 1.5302x; 1.5302x over previous
//
#include <hip/hip_runtime.h>
#include <hip/hip_bf16.h>
#include <math.h>

#define SEQ   1024
#define DH    64
#define KBLK  64
#define NBH   128
#define LDK   72   // LDS row stride (shorts)
#define C2    0.1803368801111244f   // 0.125 * log2(e)
#define DEFER_THR 44.0f

typedef short bf16x8 __attribute__((ext_vector_type(8)));
typedef float f32x4  __attribute__((ext_vector_type(4)));
typedef unsigned u32x4 __attribute__((ext_vector_type(4)));

__device__ inline unsigned short f2bf_rne(float f) {
    union { float f; unsigned u; } x; x.f = f;
    unsigned u = x.u;
    u += 0x7FFFu + ((u >> 16) & 1u);
    return (unsigned short)(u >> 16);
}
__device__ inline unsigned cvt_pk_bf16(float lo, float hi) {
    unsigned r;
    asm("v_cvt_pk_bf16_f32 %0, %1, %2" : "=v"(r) : "v"(lo), "v"(hi));
    return r;
}
// NOTE: operands must be DISTINCT values — never call with a==b (register
// coalescing would fuse them into one VGPR and the swap self-permutes).
__device__ inline void pl32swap(unsigned &a, unsigned &b) {
    asm("v_permlane32_swap_b32 %0, %1" : "+v"(a), "+v"(b));
}
__device__ inline void pl16swap(unsigned &a, unsigned &b) {
    asm("v_permlane16_swap_b32 %0, %1" : "+v"(a), "+v"(b));
}

// reductions over the 4 16-lane groups: allocation-independent shfl_xor path
__device__ inline float wave_red_add(float x) {
    x += __shfl_xor(x, 16);
    x += __shfl_xor(x, 32);
    return x;
}
__device__ inline float wave_red_max(float x) {
    x = fmaxf(x, __shfl_xor(x, 16));
    x = fmaxf(x, __shfl_xor(x, 32));
    return x;
}

// ---- pre-pass: K -> bf16 flat [bh][kk][d]; V -> bf16 transposed tiled [bh][kt][d][kk] ----
__global__ __launch_bounds__(256)
void conv_kv(const float* __restrict__ K, const float* __restrict__ V,
             unsigned short* __restrict__ Kb, unsigned short* __restrict__ Vt) {
    __shared__ unsigned short T[DH][LDK];
    const int kt  = blockIdx.x;
    const int bh  = blockIdx.y;
    const int tid = threadIdx.x;
    const size_t tile = ((size_t)bh * SEQ + kt * KBLK) * DH;

    const float* Ks = K + tile;
    unsigned short* Kd = Kb + tile;
    #pragma unroll
    for (int it = 0; it < 4; ++it) {
        const int e = (it * 256 + tid) * 4;
        float4 f = *(const float4*)(Ks + e);
        union { unsigned short s[4]; uint2 u; } p;
        p.s[0] = f2bf_rne(f.x); p.s[1] = f2bf_rne(f.y);
        p.s[2] = f2bf_rne(f.z); p.s[3] = f2bf_rne(f.w);
        *(uint2*)(Kd + e) = p.u;
    }
    const float* Vs = V + tile;
    #pragma unroll
    for (int it = 0; it < 4; ++it) {
        const int e = (it * 256 + tid) * 4;
        const int kk = e >> 6, d = e & 63;
        float4 f = *(const float4*)(Vs + e);
        T[d + 0][kk] = f2bf_rne(f.x);
        T[d + 1][kk] = f2bf_rne(f.y);
        T[d + 2][kk] = f2bf_rne(f.z);
        T[d + 3][kk] = f2bf_rne(f.w);
    }
    __syncthreads();
    unsigned short* Vd = Vt + tile;
    #pragma unroll
    for (int it = 0; it < 2; ++it) {
        const int e = (it * 256 + tid) * 8;
        const int d = e >> 6, kk0 = e & 63;
        uint4 o = *(const uint4*)&T[d][kk0];
        *(uint4*)(Vd + d * KBLK + kk0) = o;
    }
}

// ---- main kernel: 128-row q blocks, 32 q/wave; K via dbuf LDS, V via register
//      prefetch; l via MFMA-of-ones. NO min-waves clamp: the live set is
//      ~140-160 VGPR; __launch_bounds__(256,4) capped it at 128 and spilled
//      (round 8: WRITE_SIZE 171MB of scratch, 138us). ----
__global__ __launch_bounds__(256)
void attn_fwd(const float* __restrict__ Q,
              const unsigned short* __restrict__ Kb,
              const unsigned short* __restrict__ Vt,
              float* __restrict__ O) {
    __shared__ unsigned short Ksh[2][KBLK][LDK];

    // XCD-chunked swizzle: all 8 q-tiles of one bh on one XCD (1024 % 8 == 0)
    const int f  = blockIdx.y * 8 + blockIdx.x;
    const int w  = (f & 7) * 128 + (f >> 3);
    const int qt = w & 7;          // 0..7 (128-row tiles)
    const int bh = w >> 3;

    const int tid  = threadIdx.x;
    const int wave = tid >> 6;
    const int lane = tid & 63;
    const int lhi  = lane >> 4;
    const int llo  = lane & 15;

    const float* Qb = Q + ((size_t)bh * SEQ + qt * 128) * DH;
    float*       Ob = O + ((size_t)bh * SEQ + qt * 128) * DH;

    // Two Q fragment sets: set A = rows wave*32 + llo, set B = +16
    bf16x8 qfA[2], qfB[2];
    #pragma unroll
    for (int s = 0; s < 2; ++s) {
        const float* pa = Qb + (wave * 32 + llo) * DH + s * 32 + lhi * 8;
        const float* pb = pa + 16 * DH;
        float4 a0 = *(const float4*)(pa), a1 = *(const float4*)(pa + 4);
        float4 b0 = *(const float4*)(pb), b1 = *(const float4*)(pb + 4);
        qfA[s][0]=(short)f2bf_rne(a0.x); qfA[s][1]=(short)f2bf_rne(a0.y);
        qfA[s][2]=(short)f2bf_rne(a0.z); qfA[s][3]=(short)f2bf_rne(a0.w);
        qfA[s][4]=(short)f2bf_rne(a1.x); qfA[s][5]=(short)f2bf_rne(a1.y);
        qfA[s][6]=(short)f2bf_rne(a1.z); qfA[s][7]=(short)f2bf_rne(a1.w);
        qfB[s][0]=(short)f2bf_rne(b0.x); qfB[s][1]=(short)f2bf_rne(b0.y);
        qfB[s][2]=(short)f2bf_rne(b0.z); qfB[s][3]=(short)f2bf_rne(b0.w);
        qfB[s][4]=(short)f2bf_rne(b1.x); qfB[s][5]=(short)f2bf_rne(b1.y);
        qfB[s][6]=(short)f2bf_rne(b1.z); qfB[s][7]=(short)f2bf_rne(b1.w);
    }

    // ones B-fragment for row-sum MFMA (bf16 1.0 = 0x3F80)
    const bf16x8 ones = {0x3F80, 0x3F80, 0x3F80, 0x3F80,
                         0x3F80, 0x3F80, 0x3F80, 0x3F80};

    // K staging geometry: 256 threads x 2 uint4 per tile (64x64 shorts)
    const unsigned short* KbB = Kb + (size_t)bh * SEQ * DH;
    const unsigned short* VtB = Vt + (size_t)bh * SEQ * DH;
    const int soff = tid * 8;              // shorts
    const int srow = tid >> 3;             // 0..31
    const int scol = (tid & 7) * 8;

    // per-lane V fragment base (wave-uniform across waves -> L1 broadcast)
    const unsigned short* Vl = VtB + llo * KBLK + lhi * 8;

    // prologue: stage K tile 0 into buf 0; V tile 0 into registers
    uint4 k0r = *(const uint4*)(KbB + soff);
    uint4 k1r = *(const uint4*)(KbB + 2048 + soff);
    *(uint4*)&Ksh[0][srow][scol]      = k0r;
    *(uint4*)&Ksh[0][32 + srow][scol] = k1r;
    bf16x8 vf[4][2];
    #pragma unroll
    for (int dt = 0; dt < 4; ++dt) {
        vf[dt][0] = *(const bf16x8*)(Vl + dt * 16 * KBLK);
        vf[dt][1] = *(const bf16x8*)(Vl + dt * 16 * KBLK + 32);
    }
    __syncthreads();

    f32x4 accA[4] = {}, accB[4] = {};
    f32x4 accLA = {}, accLB = {};          // row-sums (l), same C-layout as acc
    float mCA = 0.0f, mCB = 0.0f;          // fixed (tile-0) per-row max * C2

    for (int kt = 0; kt < SEQ / KBLK; ++kt) {
        const int cur = kt & 1;

        // ---- issue next K tile's global loads (consumed by ds_write below) ----
        if (kt < 15) {
            const unsigned short* Kt = KbB + (kt + 1) * (KBLK * DH);
            k0r = *(const uint4*)(Kt + soff);
            k1r = *(const uint4*)(Kt + 2048 + soff);
        }

        // ---- QK^T: each K fragment read feeds both q-sets ----
        f32x4 stA[4] = {}, stB[4] = {};
        __builtin_amdgcn_s_setprio(1);
        #pragma unroll
        for (int t = 0; t < 4; ++t) {
            bf16x8 k0 = *(const bf16x8*)&Ksh[cur][t * 16 + llo][lhi * 8];
            bf16x8 k1 = *(const bf16x8*)&Ksh[cur][t * 16 + llo][32 + lhi * 8];
            stA[t] = __builtin_amdgcn_mfma_f32_16x16x32_bf16(k0, qfA[0], stA[t], 0, 0, 0);
            stA[t] = __builtin_amdgcn_mfma_f32_16x16x32_bf16(k1, qfA[1], stA[t], 0, 0, 0);
            stB[t] = __builtin_amdgcn_mfma_f32_16x16x32_bf16(k0, qfB[0], stB[t], 0, 0, 0);
            stB[t] = __builtin_amdgcn_mfma_f32_16x16x32_bf16(k1, qfB[1], stB[t], 0, 0, 0);
        }
        __builtin_amdgcn_s_setprio(0);

        // ---- fixed-M: per-q-row max from tile 0 (softmax shift-invariant) ----
        if (kt == 0) {
            float ta = stA[0][0], tb = stB[0][0];
            #pragma unroll
            for (int t = 0; t < 4; ++t)
                #pragma unroll
                for (int r = 0; r < 4; ++r) {
                    ta = fmaxf(ta, stA[t][r]);
                    tb = fmaxf(tb, stB[t][r]);
                }
            mCA = wave_red_max(ta) * C2;
            mCB = wave_red_max(tb) * C2;
        }

        // ---- P = exp2(S*C2 - mC), packed bf16, in-register ----
        unsigned wrA[4][2], wrB[4][2];
        #pragma unroll
        for (int t = 0; t < 4; ++t) {
            float a0 = __builtin_amdgcn_exp2f(__builtin_fmaf(stA[t][0], C2, -mCA));
            float a1 = __builtin_amdgcn_exp2f(__builtin_fmaf(stA[t][1], C2, -mCA));
            float a2 = __builtin_amdgcn_exp2f(__builtin_fmaf(stA[t][2], C2, -mCA));
            float a3 = __builtin_amdgcn_exp2f(__builtin_fmaf(stA[t][3], C2, -mCA));
            wrA[t][0] = cvt_pk_bf16(a0, a1);
            wrA[t][1] = cvt_pk_bf16(a2, a3);
            float b0 = __builtin_amdgcn_exp2f(__builtin_fmaf(stB[t][0], C2, -mCB));
            float b1 = __builtin_amdgcn_exp2f(__builtin_fmaf(stB[t][1], C2, -mCB));
            float b2 = __builtin_amdgcn_exp2f(__builtin_fmaf(stB[t][2], C2, -mCB));
            float b3 = __builtin_amdgcn_exp2f(__builtin_fmaf(stB[t][3], C2, -mCB));
            wrB[t][0] = cvt_pk_bf16(b0, b1);
            wrB[t][1] = cvt_pk_bf16(b2, b3);
        }

        // ---- in-register P relayout -> A-fragments (operands always distinct) ----
        unsigned pa0 = wrA[0][0], pb0 = wrA[1][0]; pl32swap(pa0, pb0); pl16swap(pa0, pb0);
        unsigned pa1 = wrA[0][1], pb1 = wrA[1][1]; pl32swap(pa1, pb1); pl16swap(pa1, pb1);
        unsigned pc0 = wrA[2][0], pd0 = wrA[3][0]; pl32swap(pc0, pd0); pl16swap(pc0, pd0);
        unsigned pc1 = wrA[2][1], pd1 = wrA[3][1]; pl32swap(pc1, pd1); pl16swap(pc1, pd1);
        bf16x8 afA0 = __builtin_bit_cast(bf16x8, (u32x4){pa0, pa1, pb0, pb1});
        bf16x8 afA1 = __builtin_bit_cast(bf16x8, (u32x4){pc0, pc1, pd0, pd1});
        unsigned qa0 = wrB[0][0], qb0 = wrB[1][0]; pl32swap(qa0, qb0); pl16swap(qa0, qb0);
        unsigned qa1 = wrB[0][1], qb1 = wrB[1][1]; pl32swap(qa1, qb1); pl16swap(qa1, qb1);
        unsigned qc0 = wrB[2][0], qd0 = wrB[3][0]; pl32swap(qc0, qd0); pl16swap(qc0, qd0);
        unsigned qc1 = wrB[2][1], qd1 = wrB[3][1]; pl32swap(qc1, qd1); pl16swap(qc1, qd1);
        bf16x8 afB0 = __builtin_bit_cast(bf16x8, (u32x4){qa0, qa1, qb0, qb1});
        bf16x8 afB1 = __builtin_bit_cast(bf16x8, (u32x4){qc0, qc1, qd0, qd1});

        // ---- PV from registers + l via MFMA-of-ones ----
        __builtin_amdgcn_s_setprio(1);
        #pragma unroll
        for (int dt = 0; dt < 4; ++dt) {
            accA[dt] = __builtin_amdgcn_mfma_f32_16x16x32_bf16(afA0, vf[dt][0], accA[dt], 0, 0, 0);
            accA[dt] = __builtin_amdgcn_mfma_f32_16x16x32_bf16(afA1, vf[dt][1], accA[dt], 0, 0, 0);
            accB[dt] = __builtin_amdgcn_mfma_f32_16x16x32_bf16(afB0, vf[dt][0], accB[dt], 0, 0, 0);
            accB[dt] = __builtin_amdgcn_mfma_f32_16x16x32_bf16(afB1, vf[dt][1], accB[dt], 0, 0, 0);
        }
        accLA = __builtin_amdgcn_mfma_f32_16x16x32_bf16(afA0, ones, accLA, 0, 0, 0);
        accLA = __builtin_amdgcn_mfma_f32_16x16x32_bf16(afA1, ones, accLA, 0, 0, 0);
        accLB = __builtin_amdgcn_mfma_f32_16x16x32_bf16(afB0, ones, accLB, 0, 0, 0);
        accLB = __builtin_amdgcn_mfma_f32_16x16x32_bf16(afB1, ones, accLB, 0, 0, 0);
        __builtin_amdgcn_s_setprio(0);

        // ---- V prefetch for t+1 into the SAME registers (PV already read them);
        //      consumed next iter after QK+softmax -> latency hidden ----
        if (kt < 15) {
            const unsigned short* Vp = Vl + (kt + 1) * (KBLK * DH);
            #pragma unroll
            for (int dt = 0; dt < 4; ++dt) {
                vf[dt][0] = *(const bf16x8*)(Vp + dt * 16 * KBLK);
                vf[dt][1] = *(const bf16x8*)(Vp + dt * 16 * KBLK + 32);
            }
        }

        // ---- write next K tile into the other buffer; single barrier ----
        if (kt < 15) {
            const int nxt = cur ^ 1;
            *(uint4*)&Ksh[nxt][srow][scol]      = k0r;
            *(uint4*)&Ksh[nxt][32 + srow][scol] = k1r;
        }
        __syncthreads();
    }

    // ---- epilogue: accL already in acc's C-layout -> direct divide, no shfl ----
    #pragma unroll
    for (int r = 0; r < 4; ++r) {
        const float la = 1.0f / accLA[r];
        const float lb = 1.0f / accLB[r];
        const int rowA = wave * 32 + lhi * 4 + r;
        #pragma unroll
        for (int dt = 0; dt < 4; ++dt) {
            Ob[rowA * DH + dt * 16 + llo]        = accA[dt][r] * la;
            Ob[(rowA + 16) * DH + dt * 16 + llo] = accB[dt][r] * lb;
        }
    }
}

// ---- fallback (ws too small): round-5 self-staging kernel ----
__global__ __launch_bounds__(256)
void attn_fwd_fb(const float* __restrict__ Q, const float* __restrict__ K,
                 const float* __restrict__ V, float* __restrict__ O) {
    __shared__ unsigned short Ksh[KBLK][LDK];
    __shared__ unsigned short Vsh[DH][LDK];

    const int f  = blockIdx.y * 16 + blockIdx.x;
    const int w  = (f & 7) * 256 + (f >> 3);
    const int qt = w & 15;
    const int bh = w >> 4;

    const int tid  = threadIdx.x;
    const int wave = tid >> 6;
    const int lane = tid & 63;
    const int lhi  = lane >> 4;
    const int llo  = lane & 15;
    const int base = lane & 48;

    const float* Qb = Q + ((size_t)bh * SEQ + qt * 64) * DH;
    float*       Ob = O + ((size_t)bh * SEQ + qt * 64) * DH;

    bf16x8 qf[2];
    #pragma unroll
    for (int s = 0; s < 2; ++s) {
        const float* p = Qb + (wave * 16 + llo) * DH + s * 32 + lhi * 8;
        float4 f0 = *(const float4*)(p), f1 = *(const float4*)(p + 4);
        qf[s][0]=(short)f2bf_rne(f0.x); qf[s][1]=(short)f2bf_rne(f0.y);
        qf[s][2]=(short)f2bf_rne(f0.z); qf[s][3]=(short)f2bf_rne(f0.w);
        qf[s][4]=(short)f2bf_rne(f1.x); qf[s][5]=(short)f2bf_rne(f1.y);
        qf[s][6]=(short)f2bf_rne(f1.z); qf[s][7]=(short)f2bf_rne(f1.w);
    }

    f32x4 acc[4] = {};
    float m_run = -INFINITY, l_run = 0.0f;

    for (int kt = 0; kt < SEQ / KBLK; ++kt) {
        __syncthreads();
        {
            const float* Kt = K + ((size_t)bh * SEQ + kt * KBLK) * DH;
            const float* Vs = V + ((size_t)bh * SEQ + kt * KBLK) * DH;
            #pragma unroll
            for (int it = 0; it < 4; ++it) {
                const int e  = (it * 256 + tid) * 4;
                const int kk = e >> 6, d = e & 63;
                float4 kv = *(const float4*)(Kt + e);
                union { unsigned short s[4]; uint2 u; } pk;
                pk.s[0] = f2bf_rne(kv.x); pk.s[1] = f2bf_rne(kv.y);
                pk.s[2] = f2bf_rne(kv.z); pk.s[3] = f2bf_rne(kv.w);
                *(uint2*)&Ksh[kk][d] = pk.u;
                float4 vv = *(const float4*)(Vs + e);
                Vsh[d + 0][kk] = f2bf_rne(vv.x);
                Vsh[d + 1][kk] = f2bf_rne(vv.y);
                Vsh[d + 2][kk] = f2bf_rne(vv.z);
                Vsh[d + 3][kk] = f2bf_rne(vv.w);
            }
        }
        __syncthreads();

        f32x4 st[4] = {};
        #pragma unroll
        for (int t = 0; t < 4; ++t) {
            bf16x8 k0 = *(const bf16x8*)&Ksh[t * 16 + llo][lhi * 8];
            bf16x8 k1 = *(const bf16x8*)&Ksh[t * 16 + llo][32 + lhi * 8];
            st[t] = __builtin_amdgcn_mfma_f32_16x16x32_bf16(k0, qf[0], st[t], 0, 0, 0);
            st[t] = __builtin_amdgcn_mfma_f32_16x16x32_bf16(k1, qf[1], st[t], 0, 0, 0);
        }

        float tmax = st[0][0];
        #pragma unroll
        for (int t = 0; t < 4; ++t)
            #pragma unroll
            for (int r = 0; r < 4; ++r) tmax = fmaxf(tmax, st[t][r]);
        tmax = wave_red_max(tmax);

        if (__any(tmax > m_run + DEFER_THR)) {
            float mn   = fmaxf(m_run, tmax);
            float corr = exp2f((m_run - mn) * C2);
            m_run = mn;
            l_run *= corr;
            #pragma unroll
            for (int r = 0; r < 4; ++r) {
                float cr = __shfl(corr, base | (lhi * 4 + r));
                #pragma unroll
                for (int dt = 0; dt < 4; ++dt) acc[dt][r] *= cr;
            }
        }

        const float mC = m_run * C2;
        float tsum = 0.0f;
        unsigned wreg[4][2];
        #pragma unroll
        for (int t = 0; t < 4; ++t) {
            float p0 = __builtin_amdgcn_exp2f(__builtin_fmaf(st[t][0], C2, -mC));
            float p1 = __builtin_amdgcn_exp2f(__builtin_fmaf(st[t][1], C2, -mC));
            float p2 = __builtin_amdgcn_exp2f(__builtin_fmaf(st[t][2], C2, -mC));
            float p3 = __builtin_amdgcn_exp2f(__builtin_fmaf(st[t][3], C2, -mC));
            tsum += (p0 + p1) + (p2 + p3);
            wreg[t][0] = cvt_pk_bf16(p0, p1);
            wreg[t][1] = cvt_pk_bf16(p2, p3);
        }
        l_run += wave_red_add(tsum);

        unsigned a0 = wreg[0][0], b0 = wreg[1][0]; pl32swap(a0, b0); pl16swap(a0, b0);
        unsigned a1 = wreg[0][1], b1 = wreg[1][1]; pl32swap(a1, b1); pl16swap(a1, b1);
        unsigned c0 = wreg[2][0], d0 = wreg[3][0]; pl32swap(c0, d0); pl16swap(c0, d0);
        unsigned c1 = wreg[2][1], d1 = wreg[3][1]; pl32swap(c1, d1); pl16swap(c1, d1);
        bf16x8 af0 = __builtin_bit_cast(bf16x8, (u32x4){a0, a1, b0, b1});
        bf16x8 af1 = __builtin_bit_cast(bf16x8, (u32x4){c0, c1, d0, d1});

        #pragma unroll
        for (int dt = 0; dt < 4; ++dt) {
            bf16x8 v0 = *(const bf16x8*)&Vsh[dt * 16 + llo][lhi * 8];
            bf16x8 v1 = *(const bf16x8*)&Vsh[dt * 16 + llo][32 + lhi * 8];
            acc[dt] = __builtin_amdgcn_mfma_f32_16x16x32_bf16(af0, v0, acc[dt], 0, 0, 0);
            acc[dt] = __builtin_amdgcn_mfma_f32_16x16x32_bf16(af1, v1, acc[dt], 0, 0, 0);
        }
    }

    const float linv = 1.0f / l_run;
    #pragma unroll
    for (int r = 0; r < 4; ++r) {
        const float lr = __shfl(linv, base | (lhi * 4 + r));
        const int row = wave * 16 + lhi * 4 + r;
        #pragma unroll
        for (int dt = 0; dt < 4; ++dt)
            Ob[row * DH + dt * 16 + llo] = acc[dt][r] * lr;
    }
}

extern "C" void kernel_launch(void* const* d_in, const int* in_sizes, int n_in,
                              void* d_out, int out_size, void* d_ws, size_t ws_size,
                              hipStream_t stream) {
    const float* q = (const float*)d_in[0];
    const float* k = (const float*)d_in[1];
    const float* v = (const float*)d_in[2];
    float* o = (float*)d_out;

    const size_t nkv = (size_t)NBH * SEQ * DH;
    dim3 block(256);

    if (ws_size >= 2 * nkv * sizeof(unsigned short)) {
        unsigned short* Kb = (unsigned short*)d_ws;
        unsigned short* Vt = Kb + nkv;
        dim3 cgrid(SEQ / KBLK, NBH);
        conv_kv<<<cgrid, block, 0, stream>>>(k, v, Kb, Vt);
        dim3 agrid(SEQ / 128, NBH);
        attn_fwd<<<agrid, block, 0, stream>>>(q, Kb, Vt, o);
    } else {
        dim3 fgrid(SEQ / 64, NBH);
        attn_fwd_fb<<<fgrid, block, 0, stream>>>(q, k, v, o);
    }
}

// Round 10
// 70.660 us; speedup vs baseline: 1.9521x; 1.2758x over previous
//
#include <hip/hip_runtime.h>
#include <hip/hip_bf16.h>
#include <math.h>

#define SEQ   1024
#define DH    64
#define KBLK  64
#define NBH   128
#define LDK   72   // LDS row stride (shorts)
#define C2    0.1803368801111244f   // 0.125 * log2(e)
#define DEFER_THR 44.0f

typedef short bf16x8 __attribute__((ext_vector_type(8)));
typedef float f32x4  __attribute__((ext_vector_type(4)));
typedef unsigned u32x4 __attribute__((ext_vector_type(4)));

__device__ inline unsigned short f2bf_rne(float f) {
    union { float f; unsigned u; } x; x.f = f;
    unsigned u = x.u;
    u += 0x7FFFu + ((u >> 16) & 1u);
    return (unsigned short)(u >> 16);
}
__device__ inline unsigned cvt_pk_bf16(float lo, float hi) {
    unsigned r;
    asm("v_cvt_pk_bf16_f32 %0, %1, %2" : "=v"(r) : "v"(lo), "v"(hi));
    return r;
}
// NOTE: operands must be DISTINCT values — never call with a==b (register
// coalescing would fuse them into one VGPR and the swap self-permutes).
__device__ inline void pl32swap(unsigned &a, unsigned &b) {
    asm("v_permlane32_swap_b32 %0, %1" : "+v"(a), "+v"(b));
}
__device__ inline void pl16swap(unsigned &a, unsigned &b) {
    asm("v_permlane16_swap_b32 %0, %1" : "+v"(a), "+v"(b));
}

// reductions over the 4 16-lane groups: allocation-independent shfl_xor path
__device__ inline float wave_red_add(float x) {
    x += __shfl_xor(x, 16);
    x += __shfl_xor(x, 32);
    return x;
}
__device__ inline float wave_red_max(float x) {
    x = fmaxf(x, __shfl_xor(x, 16));
    x = fmaxf(x, __shfl_xor(x, 32));
    return x;
}

// ---- pre-pass: K -> bf16 flat [bh][kk][d]; V -> bf16 transposed tiled [bh][kt][d][kk] ----
__global__ __launch_bounds__(256)
void conv_kv(const float* __restrict__ K, const float* __restrict__ V,
             unsigned short* __restrict__ Kb, unsigned short* __restrict__ Vt) {
    __shared__ unsigned short T[DH][LDK];
    const int kt  = blockIdx.x;
    const int bh  = blockIdx.y;
    const int tid = threadIdx.x;
    const size_t tile = ((size_t)bh * SEQ + kt * KBLK) * DH;

    const float* Ks = K + tile;
    unsigned short* Kd = Kb + tile;
    #pragma unroll
    for (int it = 0; it < 4; ++it) {
        const int e = (it * 256 + tid) * 4;
        float4 f = *(const float4*)(Ks + e);
        union { unsigned short s[4]; uint2 u; } p;
        p.s[0] = f2bf_rne(f.x); p.s[1] = f2bf_rne(f.y);
        p.s[2] = f2bf_rne(f.z); p.s[3] = f2bf_rne(f.w);
        *(uint2*)(Kd + e) = p.u;
    }
    const float* Vs = V + tile;
    #pragma unroll
    for (int it = 0; it < 4; ++it) {
        const int e = (it * 256 + tid) * 4;
        const int kk = e >> 6, d = e & 63;
        float4 f = *(const float4*)(Vs + e);
        T[d + 0][kk] = f2bf_rne(f.x);
        T[d + 1][kk] = f2bf_rne(f.y);
        T[d + 2][kk] = f2bf_rne(f.z);
        T[d + 3][kk] = f2bf_rne(f.w);
    }
    __syncthreads();
    unsigned short* Vd = Vt + tile;
    #pragma unroll
    for (int it = 0; it < 2; ++it) {
        const int e = (it * 256 + tid) * 8;
        const int d = e >> 6, kk0 = e & 63;
        uint4 o = *(const uint4*)&T[d][kk0];
        *(uint4*)(Vd + d * KBLK + kk0) = o;
    }
}

// ---- main kernel: 128-row q blocks, 32 q/wave; K AND V dbuf-staged in LDS
//      (round-7 empirical best; reg-resident V regressed in rounds 4/9);
//      l via MFMA-of-ones -> shfl-free epilogue. No min-waves clamp
//      (round 8: clamp at 4 waves/EU spilled, 171MB scratch). ----
__global__ __launch_bounds__(256)
void attn_fwd(const float* __restrict__ Q,
              const unsigned short* __restrict__ Kb,
              const unsigned short* __restrict__ Vt,
              float* __restrict__ O) {
    __shared__ unsigned short Ksh[2][KBLK][LDK];
    __shared__ unsigned short Vsh[2][DH][LDK];

    // XCD-chunked swizzle: all 8 q-tiles of one bh on one XCD (1024 % 8 == 0)
    const int f  = blockIdx.y * 8 + blockIdx.x;
    const int w  = (f & 7) * 128 + (f >> 3);
    const int qt = w & 7;          // 0..7 (128-row tiles)
    const int bh = w >> 3;

    const int tid  = threadIdx.x;
    const int wave = tid >> 6;
    const int lane = tid & 63;
    const int lhi  = lane >> 4;
    const int llo  = lane & 15;

    const float* Qb = Q + ((size_t)bh * SEQ + qt * 128) * DH;
    float*       Ob = O + ((size_t)bh * SEQ + qt * 128) * DH;

    // Two Q fragment sets: set A = rows wave*32 + llo, set B = +16
    bf16x8 qfA[2], qfB[2];
    #pragma unroll
    for (int s = 0; s < 2; ++s) {
        const float* pa = Qb + (wave * 32 + llo) * DH + s * 32 + lhi * 8;
        const float* pb = pa + 16 * DH;
        float4 a0 = *(const float4*)(pa), a1 = *(const float4*)(pa + 4);
        float4 b0 = *(const float4*)(pb), b1 = *(const float4*)(pb + 4);
        qfA[s][0]=(short)f2bf_rne(a0.x); qfA[s][1]=(short)f2bf_rne(a0.y);
        qfA[s][2]=(short)f2bf_rne(a0.z); qfA[s][3]=(short)f2bf_rne(a0.w);
        qfA[s][4]=(short)f2bf_rne(a1.x); qfA[s][5]=(short)f2bf_rne(a1.y);
        qfA[s][6]=(short)f2bf_rne(a1.z); qfA[s][7]=(short)f2bf_rne(a1.w);
        qfB[s][0]=(short)f2bf_rne(b0.x); qfB[s][1]=(short)f2bf_rne(b0.y);
        qfB[s][2]=(short)f2bf_rne(b0.z); qfB[s][3]=(short)f2bf_rne(b0.w);
        qfB[s][4]=(short)f2bf_rne(b1.x); qfB[s][5]=(short)f2bf_rne(b1.y);
        qfB[s][6]=(short)f2bf_rne(b1.z); qfB[s][7]=(short)f2bf_rne(b1.w);
    }

    // ones B-fragment for row-sum MFMA (bf16 1.0 = 0x3F80)
    const bf16x8 ones = {0x3F80, 0x3F80, 0x3F80, 0x3F80,
                         0x3F80, 0x3F80, 0x3F80, 0x3F80};

    // staging geometry: 256 threads x 2 uint4 per array per tile (64x64 shorts)
    const unsigned short* KbB = Kb + (size_t)bh * SEQ * DH;
    const unsigned short* VtB = Vt + (size_t)bh * SEQ * DH;
    const int soff = tid * 8;              // shorts
    const int srow = tid >> 3;             // 0..31
    const int scol = (tid & 7) * 8;

    // prologue: stage tile 0 into buf 0
    uint4 k0r = *(const uint4*)(KbB + soff);
    uint4 k1r = *(const uint4*)(KbB + 2048 + soff);
    uint4 v0r = *(const uint4*)(VtB + soff);
    uint4 v1r = *(const uint4*)(VtB + 2048 + soff);
    *(uint4*)&Ksh[0][srow][scol]      = k0r;
    *(uint4*)&Ksh[0][32 + srow][scol] = k1r;
    *(uint4*)&Vsh[0][srow][scol]      = v0r;
    *(uint4*)&Vsh[0][32 + srow][scol] = v1r;
    __syncthreads();

    f32x4 accA[4] = {}, accB[4] = {};
    f32x4 accLA = {}, accLB = {};          // row-sums (l), same C-layout as acc
    float mCA = 0.0f, mCB = 0.0f;          // fixed (tile-0) per-row max * C2

    for (int kt = 0; kt < SEQ / KBLK; ++kt) {
        const int cur = kt & 1;

        // ---- issue next tile's global loads (consumed by ds_write below) ----
        if (kt < 15) {
            const unsigned short* Kt = KbB + (kt + 1) * (KBLK * DH);
            const unsigned short* Vp = VtB + (kt + 1) * (KBLK * DH);
            k0r = *(const uint4*)(Kt + soff);
            k1r = *(const uint4*)(Kt + 2048 + soff);
            v0r = *(const uint4*)(Vp + soff);
            v1r = *(const uint4*)(Vp + 2048 + soff);
        }

        // ---- QK^T: each K fragment read feeds both q-sets ----
        f32x4 stA[4] = {}, stB[4] = {};
        __builtin_amdgcn_s_setprio(1);
        #pragma unroll
        for (int t = 0; t < 4; ++t) {
            bf16x8 k0 = *(const bf16x8*)&Ksh[cur][t * 16 + llo][lhi * 8];
            bf16x8 k1 = *(const bf16x8*)&Ksh[cur][t * 16 + llo][32 + lhi * 8];
            stA[t] = __builtin_amdgcn_mfma_f32_16x16x32_bf16(k0, qfA[0], stA[t], 0, 0, 0);
            stA[t] = __builtin_amdgcn_mfma_f32_16x16x32_bf16(k1, qfA[1], stA[t], 0, 0, 0);
            stB[t] = __builtin_amdgcn_mfma_f32_16x16x32_bf16(k0, qfB[0], stB[t], 0, 0, 0);
            stB[t] = __builtin_amdgcn_mfma_f32_16x16x32_bf16(k1, qfB[1], stB[t], 0, 0, 0);
        }
        __builtin_amdgcn_s_setprio(0);

        // ---- fixed-M: per-q-row max from tile 0 (softmax shift-invariant) ----
        if (kt == 0) {
            float ta = stA[0][0], tb = stB[0][0];
            #pragma unroll
            for (int t = 0; t < 4; ++t)
                #pragma unroll
                for (int r = 0; r < 4; ++r) {
                    ta = fmaxf(ta, stA[t][r]);
                    tb = fmaxf(tb, stB[t][r]);
                }
            mCA = wave_red_max(ta) * C2;
            mCB = wave_red_max(tb) * C2;
        }

        // ---- P = exp2(S*C2 - mC), packed bf16, in-register ----
        unsigned wrA[4][2], wrB[4][2];
        #pragma unroll
        for (int t = 0; t < 4; ++t) {
            float a0 = __builtin_amdgcn_exp2f(__builtin_fmaf(stA[t][0], C2, -mCA));
            float a1 = __builtin_amdgcn_exp2f(__builtin_fmaf(stA[t][1], C2, -mCA));
            float a2 = __builtin_amdgcn_exp2f(__builtin_fmaf(stA[t][2], C2, -mCA));
            float a3 = __builtin_amdgcn_exp2f(__builtin_fmaf(stA[t][3], C2, -mCA));
            wrA[t][0] = cvt_pk_bf16(a0, a1);
            wrA[t][1] = cvt_pk_bf16(a2, a3);
            float b0 = __builtin_amdgcn_exp2f(__builtin_fmaf(stB[t][0], C2, -mCB));
            float b1 = __builtin_amdgcn_exp2f(__builtin_fmaf(stB[t][1], C2, -mCB));
            float b2 = __builtin_amdgcn_exp2f(__builtin_fmaf(stB[t][2], C2, -mCB));
            float b3 = __builtin_amdgcn_exp2f(__builtin_fmaf(stB[t][3], C2, -mCB));
            wrB[t][0] = cvt_pk_bf16(b0, b1);
            wrB[t][1] = cvt_pk_bf16(b2, b3);
        }

        // ---- in-register P relayout -> A-fragments (operands always distinct) ----
        unsigned pa0 = wrA[0][0], pb0 = wrA[1][0]; pl32swap(pa0, pb0); pl16swap(pa0, pb0);
        unsigned pa1 = wrA[0][1], pb1 = wrA[1][1]; pl32swap(pa1, pb1); pl16swap(pa1, pb1);
        unsigned pc0 = wrA[2][0], pd0 = wrA[3][0]; pl32swap(pc0, pd0); pl16swap(pc0, pd0);
        unsigned pc1 = wrA[2][1], pd1 = wrA[3][1]; pl32swap(pc1, pd1); pl16swap(pc1, pd1);
        bf16x8 afA0 = __builtin_bit_cast(bf16x8, (u32x4){pa0, pa1, pb0, pb1});
        bf16x8 afA1 = __builtin_bit_cast(bf16x8, (u32x4){pc0, pc1, pd0, pd1});
        unsigned qa0 = wrB[0][0], qb0 = wrB[1][0]; pl32swap(qa0, qb0); pl16swap(qa0, qb0);
        unsigned qa1 = wrB[0][1], qb1 = wrB[1][1]; pl32swap(qa1, qb1); pl16swap(qa1, qb1);
        unsigned qc0 = wrB[2][0], qd0 = wrB[3][0]; pl32swap(qc0, qd0); pl16swap(qc0, qd0);
        unsigned qc1 = wrB[2][1], qd1 = wrB[3][1]; pl32swap(qc1, qd1); pl16swap(qc1, qd1);
        bf16x8 afB0 = __builtin_bit_cast(bf16x8, (u32x4){qa0, qa1, qb0, qb1});
        bf16x8 afB1 = __builtin_bit_cast(bf16x8, (u32x4){qc0, qc1, qd0, qd1});

        // ---- PV from LDS + l via MFMA-of-ones ----
        __builtin_amdgcn_s_setprio(1);
        #pragma unroll
        for (int dt = 0; dt < 4; ++dt) {
            bf16x8 v0 = *(const bf16x8*)&Vsh[cur][dt * 16 + llo][lhi * 8];
            bf16x8 v1 = *(const bf16x8*)&Vsh[cur][dt * 16 + llo][32 + lhi * 8];
            accA[dt] = __builtin_amdgcn_mfma_f32_16x16x32_bf16(afA0, v0, accA[dt], 0, 0, 0);
            accA[dt] = __builtin_amdgcn_mfma_f32_16x16x32_bf16(afA1, v1, accA[dt], 0, 0, 0);
            accB[dt] = __builtin_amdgcn_mfma_f32_16x16x32_bf16(afB0, v0, accB[dt], 0, 0, 0);
            accB[dt] = __builtin_amdgcn_mfma_f32_16x16x32_bf16(afB1, v1, accB[dt], 0, 0, 0);
        }
        accLA = __builtin_amdgcn_mfma_f32_16x16x32_bf16(afA0, ones, accLA, 0, 0, 0);
        accLA = __builtin_amdgcn_mfma_f32_16x16x32_bf16(afA1, ones, accLA, 0, 0, 0);
        accLB = __builtin_amdgcn_mfma_f32_16x16x32_bf16(afB0, ones, accLB, 0, 0, 0);
        accLB = __builtin_amdgcn_mfma_f32_16x16x32_bf16(afB1, ones, accLB, 0, 0, 0);
        __builtin_amdgcn_s_setprio(0);

        // ---- write next tile into the other buffer; single barrier ----
        if (kt < 15) {
            const int nxt = cur ^ 1;
            *(uint4*)&Ksh[nxt][srow][scol]      = k0r;
            *(uint4*)&Ksh[nxt][32 + srow][scol] = k1r;
            *(uint4*)&Vsh[nxt][srow][scol]      = v0r;
            *(uint4*)&Vsh[nxt][32 + srow][scol] = v1r;
        }
        __syncthreads();
    }

    // ---- epilogue: accL already in acc's C-layout -> direct divide, no shfl ----
    #pragma unroll
    for (int r = 0; r < 4; ++r) {
        const float la = 1.0f / accLA[r];
        const float lb = 1.0f / accLB[r];
        const int rowA = wave * 32 + lhi * 4 + r;
        #pragma unroll
        for (int dt = 0; dt < 4; ++dt) {
            Ob[rowA * DH + dt * 16 + llo]        = accA[dt][r] * la;
            Ob[(rowA + 16) * DH + dt * 16 + llo] = accB[dt][r] * lb;
        }
    }
}

// ---- fallback (ws too small): round-5 self-staging kernel ----
__global__ __launch_bounds__(256)
void attn_fwd_fb(const float* __restrict__ Q, const float* __restrict__ K,
                 const float* __restrict__ V, float* __restrict__ O) {
    __shared__ unsigned short Ksh[KBLK][LDK];
    __shared__ unsigned short Vsh[DH][LDK];

    const int f  = blockIdx.y * 16 + blockIdx.x;
    const int w  = (f & 7) * 256 + (f >> 3);
    const int qt = w & 15;
    const int bh = w >> 4;

    const int tid  = threadIdx.x;
    const int wave = tid >> 6;
    const int lane = tid & 63;
    const int lhi  = lane >> 4;
    const int llo  = lane & 15;
    const int base = lane & 48;

    const float* Qb = Q + ((size_t)bh * SEQ + qt * 64) * DH;
    float*       Ob = O + ((size_t)bh * SEQ + qt * 64) * DH;

    bf16x8 qf[2];
    #pragma unroll
    for (int s = 0; s < 2; ++s) {
        const float* p = Qb + (wave * 16 + llo) * DH + s * 32 + lhi * 8;
        float4 f0 = *(const float4*)(p), f1 = *(const float4*)(p + 4);
        qf[s][0]=(short)f2bf_rne(f0.x); qf[s][1]=(short)f2bf_rne(f0.y);
        qf[s][2]=(short)f2bf_rne(f0.z); qf[s][3]=(short)f2bf_rne(f0.w);
        qf[s][4]=(short)f2bf_rne(f1.x); qf[s][5]=(short)f2bf_rne(f1.y);
        qf[s][6]=(short)f2bf_rne(f1.z); qf[s][7]=(short)f2bf_rne(f1.w);
    }

    f32x4 acc[4] = {};
    float m_run = -INFINITY, l_run = 0.0f;

    for (int kt = 0; kt < SEQ / KBLK; ++kt) {
        __syncthreads();
        {
            const float* Kt = K + ((size_t)bh * SEQ + kt * KBLK) * DH;
            const float* Vs = V + ((size_t)bh * SEQ + kt * KBLK) * DH;
            #pragma unroll
            for (int it = 0; it < 4; ++it) {
                const int e  = (it * 256 + tid) * 4;
                const int kk = e >> 6, d = e & 63;
                float4 kv = *(const float4*)(Kt + e);
                union { unsigned short s[4]; uint2 u; } pk;
                pk.s[0] = f2bf_rne(kv.x); pk.s[1] = f2bf_rne(kv.y);
                pk.s[2] = f2bf_rne(kv.z); pk.s[3] = f2bf_rne(kv.w);
                *(uint2*)&Ksh[kk][d] = pk.u;
                float4 vv = *(const float4*)(Vs + e);
                Vsh[d + 0][kk] = f2bf_rne(vv.x);
                Vsh[d + 1][kk] = f2bf_rne(vv.y);
                Vsh[d + 2][kk] = f2bf_rne(vv.z);
                Vsh[d + 3][kk] = f2bf_rne(vv.w);
            }
        }
        __syncthreads();

        f32x4 st[4] = {};
        #pragma unroll
        for (int t = 0; t < 4; ++t) {
            bf16x8 k0 = *(const bf16x8*)&Ksh[t * 16 + llo][lhi * 8];
            bf16x8 k1 = *(const bf16x8*)&Ksh[t * 16 + llo][32 + lhi * 8];
            st[t] = __builtin_amdgcn_mfma_f32_16x16x32_bf16(k0, qf[0], st[t], 0, 0, 0);
            st[t] = __builtin_amdgcn_mfma_f32_16x16x32_bf16(k1, qf[1], st[t], 0, 0, 0);
        }

        float tmax = st[0][0];
        #pragma unroll
        for (int t = 0; t < 4; ++t)
            #pragma unroll
            for (int r = 0; r < 4; ++r) tmax = fmaxf(tmax, st[t][r]);
        tmax = wave_red_max(tmax);

        if (__any(tmax > m_run + DEFER_THR)) {
            float mn   = fmaxf(m_run, tmax);
            float corr = exp2f((m_run - mn) * C2);
            m_run = mn;
            l_run *= corr;
            #pragma unroll
            for (int r = 0; r < 4; ++r) {
                float cr = __shfl(corr, base | (lhi * 4 + r));
                #pragma unroll
                for (int dt = 0; dt < 4; ++dt) acc[dt][r] *= cr;
            }
        }

        const float mC = m_run * C2;
        float tsum = 0.0f;
        unsigned wreg[4][2];
        #pragma unroll
        for (int t = 0; t < 4; ++t) {
            float p0 = __builtin_amdgcn_exp2f(__builtin_fmaf(st[t][0], C2, -mC));
            float p1 = __builtin_amdgcn_exp2f(__builtin_fmaf(st[t][1], C2, -mC));
            float p2 = __builtin_amdgcn_exp2f(__builtin_fmaf(st[t][2], C2, -mC));
            float p3 = __builtin_amdgcn_exp2f(__builtin_fmaf(st[t][3], C2, -mC));
            tsum += (p0 + p1) + (p2 + p3);
            wreg[t][0] = cvt_pk_bf16(p0, p1);
            wreg[t][1] = cvt_pk_bf16(p2, p3);
        }
        l_run += wave_red_add(tsum);

        unsigned a0 = wreg[0][0], b0 = wreg[1][0]; pl32swap(a0, b0); pl16swap(a0, b0);
        unsigned a1 = wreg[0][1], b1 = wreg[1][1]; pl32swap(a1, b1); pl16swap(a1, b1);
        unsigned c0 = wreg[2][0], d0 = wreg[3][0]; pl32swap(c0, d0); pl16swap(c0, d0);
        unsigned c1 = wreg[2][1], d1 = wreg[3][1]; pl32swap(c1, d1); pl16swap(c1, d1);
        bf16x8 af0 = __builtin_bit_cast(bf16x8, (u32x4){a0, a1, b0, b1});
        bf16x8 af1 = __builtin_bit_cast(bf16x8, (u32x4){c0, c1, d0, d1});

        #pragma unroll
        for (int dt = 0; dt < 4; ++dt) {
            bf16x8 v0 = *(const bf16x8*)&Vsh[dt * 16 + llo][lhi * 8];
            bf16x8 v1 = *(const bf16x8*)&Vsh[dt * 16 + llo][32 + lhi * 8];
            acc[dt] = __builtin_amdgcn_mfma_f32_16x16x32_bf16(af0, v0, acc[dt], 0, 0, 0);
            acc[dt] = __builtin_amdgcn_mfma_f32_16x16x32_bf16(af1, v1, acc[dt], 0, 0, 0);
        }
    }

    const float linv = 1.0f / l_run;
    #pragma unroll
    for (int r = 0; r < 4; ++r) {
        const float lr = __shfl(linv, base | (lhi * 4 + r));
        const int row = wave * 16 + lhi * 4 + r;
        #pragma unroll
        for (int dt = 0; dt < 4; ++dt)
            Ob[row * DH + dt * 16 + llo] = acc[dt][r] * lr;
    }
}

extern "C" void kernel_launch(void* const* d_in, const int* in_sizes, int n_in,
                              void* d_out, int out_size, void* d_ws, size_t ws_size,
                              hipStream_t stream) {
    const float* q = (const float*)d_in[0];
    const float* k = (const float*)d_in[1];
    const float* v = (const float*)d_in[2];
    float* o = (float*)d_out;

    const size_t nkv = (size_t)NBH * SEQ * DH;
    dim3 block(256);

    if (ws_size >= 2 * nkv * sizeof(unsigned short)) {
        unsigned short* Kb = (unsigned short*)d_ws;
        unsigned short* Vt = Kb + nkv;
        dim3 cgrid(SEQ / KBLK, NBH);
        conv_kv<<<cgrid, block, 0, stream>>>(k, v, Kb, Vt);
        dim3 agrid(SEQ / 128, NBH);
        attn_fwd<<<agrid, block, 0, stream>>>(q, Kb, Vt, o);
    } else {
        dim3 fgrid(SEQ / 64, NBH);
        attn_fwd_fb<<<fgrid, block, 0, stream>>>(q, k, v, o);
    }
}